// Round 2
// baseline (98.891 us; speedup 1.0000x reference)
//
#include <hip/hip_runtime.h>
#include <math.h>

#define C_IN  32
#define O_OUT 32
#define HIMG  112
#define WIMG  112
#define TI    16    // spatial tile rows
#define TJ    16    // spatial tile cols
#define OG    4     // output channels per wave-group (4 waves x 4 = 16 per block)
#define LROW  20    // padded LDS row stride (18 used), multiple of 4 for b128 alignment
#define LPLANE (18 * LROW)

// Tropical (max-min) 3x3 conv, 'same' padding with -inf.
// out[n,o,i,j] = max_{c,kh,kw} min(x[n,c,i+kh-1,j+kw-1], w[o,c,kh,kw])
__global__ __launch_bounds__(256, 3) void semiconv_kernel(
    const float* __restrict__ x, const float* __restrict__ kern,
    float* __restrict__ out)
{
    __shared__ __align__(16) float lds[C_IN * LPLANE];   // 46080 B -> 3 blocks/CU

    const int tid = threadIdx.x;
    const int tj0 = blockIdx.x * TJ;
    const int ti0 = blockIdx.y * TI;
    const int n   = blockIdx.z >> 1;
    const int oh  = blockIdx.z & 1;

    const float* xn = x + (size_t)n * (C_IN * HIMG * WIMG);

    // Stage x[n, :, ti0-1 .. ti0+16, tj0-1 .. tj0+16] into padded LDS tile,
    // -inf outside the image (and in the 2 pad columns, which are never read).
    #pragma unroll 1
    for (int idx = tid; idx < C_IN * LPLANE; idx += 256) {
        int c   = idx / LPLANE;
        int rem = idx - c * LPLANE;
        int r   = rem / LROW;
        int col = rem - r * LROW;
        int gi = ti0 - 1 + r;
        int gj = tj0 - 1 + col;
        float v = -INFINITY;
        if (col < 18 && (unsigned)gi < (unsigned)HIMG && (unsigned)gj < (unsigned)WIMG)
            v = xn[c * (HIMG * WIMG) + gi * WIMG + gj];
        lds[idx] = v;
    }
    __syncthreads();

    const int lane = tid & 63;
    const int wv   = tid >> 6;                 // wave id 0..3
    // wave-uniform o-group base, provably uniform -> weight loads become s_load
    const int o0   = __builtin_amdgcn_readfirstlane(oh * 16 + wv * OG);
    const int rr   = lane >> 2;                // output row within tile, 0..15
    const int q0   = (lane & 3) * 4;           // output col base: 0,4,8,12

    float acc[OG][4];
    #pragma unroll
    for (int a = 0; a < OG; ++a)
        #pragma unroll
        for (int b = 0; b < 4; ++b) acc[a][b] = -INFINITY;

    const float* wbase = kern + (size_t)o0 * (C_IN * 9);

    #pragma unroll 2
    for (int c = 0; c < C_IN; ++c) {
        // 6 contiguous taps per row (cols q0 .. q0+5 of haloed tile), 3 rows.
        // q0 is 16B-aligned and LROW%4==0 -> ds_read_b128 + ds_read_b64 per row.
        const float* xs = &lds[c * LPLANE + rr * LROW + q0];
        float xv[3][6];
        #pragma unroll
        for (int kh = 0; kh < 3; ++kh) {
            float4 a4 = *(const float4*)(xs + kh * LROW);
            float2 b2 = *(const float2*)(xs + kh * LROW + 4);
            xv[kh][0] = a4.x; xv[kh][1] = a4.y; xv[kh][2] = a4.z; xv[kh][3] = a4.w;
            xv[kh][4] = b2.x; xv[kh][5] = b2.y;
        }
        #pragma unroll
        for (int oo = 0; oo < OG; ++oo) {
            const float* wp = wbase + (size_t)oo * (C_IN * 9) + c * 9;  // uniform
            float w0 = wp[0], w1 = wp[1], w2 = wp[2],
                  w3 = wp[3], w4 = wp[4], w5 = wp[5],
                  w6 = wp[6], w7 = wp[7], w8 = wp[8];
            #pragma unroll
            for (int q = 0; q < 4; ++q) {
                float t0 = fminf(xv[0][q + 0], w0);
                float t1 = fminf(xv[0][q + 1], w1);
                float t2 = fminf(xv[0][q + 2], w2);
                float t3 = fminf(xv[1][q + 0], w3);
                float t4 = fminf(xv[1][q + 1], w4);
                float t5 = fminf(xv[1][q + 2], w5);
                float t6 = fminf(xv[2][q + 0], w6);
                float t7 = fminf(xv[2][q + 1], w7);
                float t8 = fminf(xv[2][q + 2], w8);
                // fmaxf(fmaxf(a,b),c) -> v_max3_f32
                float r0 = fmaxf(fmaxf(t0, t1), t2);
                float r1 = fmaxf(fmaxf(t3, t4), t5);
                float r2 = fmaxf(fmaxf(t6, t7), t8);
                acc[oo][q] = fmaxf(acc[oo][q], fmaxf(fmaxf(r0, r1), r2));
            }
        }
    }

    #pragma unroll
    for (int oo = 0; oo < OG; ++oo) {
        float* op = out + (((size_t)(n * O_OUT + o0 + oo)) * HIMG + (ti0 + rr)) * WIMG
                        + (tj0 + q0);
        float4 v;
        v.x = acc[oo][0]; v.y = acc[oo][1]; v.z = acc[oo][2]; v.w = acc[oo][3];
        *(float4*)op = v;   // 16B-aligned: tj0+q0 is a multiple of 4
    }
}

extern "C" void kernel_launch(void* const* d_in, const int* in_sizes, int n_in,
                              void* d_out, int out_size, void* d_ws, size_t ws_size,
                              hipStream_t stream) {
    const float* x    = (const float*)d_in[0];
    const float* kern = (const float*)d_in[1];
    float* out        = (float*)d_out;
    dim3 grid(WIMG / TJ, HIMG / TI, 8 * 2);   // (7, 7, 16): n x o-half
    dim3 block(256);
    semiconv_kernel<<<grid, block, 0, stream>>>(x, kern, out);
}